// Round 1
// baseline (226.456 us; speedup 1.0000x reference)
//
#include <hip/hip_runtime.h>

// Problem constants (fixed by the reference's setup_inputs).
#define HREF   512
#define WREF   512
#define NBUCK  6
#define NLOOP  4
#define NDET   4096
#define NSAMP  128

// One thread per (det, sample) pair. Lane i within a wave handles consecutive
// samples of the same det -> det float2 loads/stores are coalesced; gathers
// are random within one batch slab (12 MB) shared by the whole wave.
__global__ __launch_bounds__(256) void CPN_4492535791617_kernel(
    const float* __restrict__ det_in,
    const float* __restrict__ refinement,
    const float* __restrict__ sampling,
    const int*   __restrict__ bsel,
    float*       __restrict__ out)
{
    const int tid = blockIdx.x * blockDim.x + threadIdx.x;   // [0, NDET*NSAMP)
    const int s = tid & (NSAMP - 1);
    const int d = tid >> 7;                                  // NSAMP == 128

    float2 det = ((const float2*)det_in)[tid];
    const int bb = bsel[d];

    // Per-sample bucket weights. off=-1 always has weight 0 (d = frac+1 >= 1),
    // so only off=0 (w0 = 1-frac) and off=+1 (w1 = frac) contribute.
    const float base = sampling[s] * (float)NBUCK;
    const float bf   = floorf(base);
    const float frac = base - bf;
    const float w0   = 1.0f - frac;
    const float w1   = frac;
    int bi = (int)bf;                 // in [0, NBUCK-1] for sampling in [0,1)
    if (bi >= NBUCK) bi -= NBUCK;     // safety
    if (bi < 0)      bi  = 0;
    int bj = bi + 1; if (bj >= NBUCK) bj -= NBUCK;

    const size_t plane = (size_t)HREF * WREF;
    const float* slab = refinement + (size_t)bb * (2 * NBUCK) * plane;
    const float* c0 = slab + (size_t)(2 * bi)     * plane;  // x-channel, bucket bi
    const float* c1 = slab + (size_t)(2 * bi + 1) * plane;  // y-channel, bucket bi
    const float* c2 = slab + (size_t)(2 * bj)     * plane;  // x-channel, bucket bj
    const float* c3 = slab + (size_t)(2 * bj + 1) * plane;  // y-channel, bucket bj

    #pragma unroll
    for (int l = 0; l < NLOOP; ++l) {
        // jnp.round == round-half-to-even == rintf (RNE default).
        float x = rintf(det.x);
        float y = rintf(det.y);
        x = fminf(fmaxf(x, 0.0f), (float)(WREF - 1));
        y = fminf(fmaxf(y, 0.0f), (float)(HREF - 1));
        const int p = (int)y * WREF + (int)x;

        const float g0 = c0[p];
        const float g2 = c2[p];
        const float g1 = c1[p];
        const float g3 = c3[p];

        det.x = x + (w0 * g0 + w1 * g2);
        det.y = y + (w0 * g1 + w1 * g3);
    }

    ((float2*)out)[tid] = det;
}

extern "C" void kernel_launch(void* const* d_in, const int* in_sizes, int n_in,
                              void* d_out, int out_size, void* d_ws, size_t ws_size,
                              hipStream_t stream) {
    const float* det_indices = (const float*)d_in[0];
    const float* refinement  = (const float*)d_in[1];
    const float* sampling    = (const float*)d_in[2];
    const int*   b           = (const int*)  d_in[3];
    float* out = (float*)d_out;

    const int total = NDET * NSAMP;          // 524288 threads
    const int block = 256;
    const int grid  = total / block;         // 2048 blocks
    CPN_4492535791617_kernel<<<grid, block, 0, stream>>>(
        det_indices, refinement, sampling, b, out);
}

// Round 2
// 139.545 us; speedup vs baseline: 1.6228x; 1.6228x over previous
//
#include <hip/hip_runtime.h>

// Problem constants (fixed by the reference's setup_inputs).
#define HREF   512
#define WREF   512
#define NBUCK  6
#define NLOOP  4
#define NDET   4096
#define NSAMP  128
#define BATCH  4
#define PLANE  (HREF * WREF)            // 262144 = 2^18
#define NCHAN  (2 * NBUCK)              // 12
#define RECSZ  16                       // floats per pixel record (12 + 4 pad = 64 B)

// ---------------------------------------------------------------------------
// Pre-pass: refinement[B][12][H][W]  ->  ws[B][H][W][16]  (64 B pixel records)
// Reads coalesced per channel; writes 4x float4 per thread (full 64 B lines).
// ---------------------------------------------------------------------------
__global__ __launch_bounds__(256) void CPN_transpose_kernel(
    const float* __restrict__ ref, float* __restrict__ ws)
{
    const int t = blockIdx.x * blockDim.x + threadIdx.x;   // [0, BATCH*PLANE)
    const int b = t >> 18;                                 // PLANE == 2^18
    const int p = t & (PLANE - 1);

    const float* src = ref + (size_t)b * NCHAN * PLANE + p;
    float* dst = ws + ((size_t)t << 4);

    float v[RECSZ];
    #pragma unroll
    for (int c = 0; c < NCHAN; ++c) v[c] = src[(size_t)c << 18];
    #pragma unroll
    for (int c = NCHAN; c < RECSZ; ++c) v[c] = 0.0f;

    #pragma unroll
    for (int c = 0; c < RECSZ; c += 4)
        *(float4*)(dst + c) = make_float4(v[c], v[c+1], v[c+2], v[c+3]);
}

// ---------------------------------------------------------------------------
// Gather loop on the interleaved layout: the 4 needed channels per pixel are
// two float2 loads from ONE 64 B record line (2nd load is an L2 hit).
// ---------------------------------------------------------------------------
__global__ __launch_bounds__(256) void CPN_4492535791617_kernel(
    const float* __restrict__ det_in,
    const float* __restrict__ ws,
    const float* __restrict__ sampling,
    const int*   __restrict__ bsel,
    float*       __restrict__ out)
{
    const int tid = blockIdx.x * blockDim.x + threadIdx.x;   // [0, NDET*NSAMP)
    const int s = tid & (NSAMP - 1);
    const int d = tid >> 7;                                  // NSAMP == 128

    float2 det = ((const float2*)det_in)[tid];
    const int bb = bsel[d];

    // off=-1 always has weight 0 (d = frac+1 >= 1): only off=0 and off=+1 remain.
    const float base = sampling[s] * (float)NBUCK;
    const float bf   = floorf(base);
    const float frac = base - bf;
    const float w0   = 1.0f - frac;
    const float w1   = frac;
    int bi = (int)bf;
    if (bi >= NBUCK) bi -= NBUCK;
    if (bi < 0)      bi  = 0;
    int bj = bi + 1; if (bj >= NBUCK) bj -= NBUCK;

    const float* slab = ws + ((size_t)bb << 18 << 4);        // batch slab of records

    #pragma unroll
    for (int l = 0; l < NLOOP; ++l) {
        // jnp.round == round-half-to-even == rintf (RNE default).
        float x = rintf(det.x);
        float y = rintf(det.y);
        x = fminf(fmaxf(x, 0.0f), (float)(WREF - 1));
        y = fminf(fmaxf(y, 0.0f), (float)(HREF - 1));
        const int p = (int)y * WREF + (int)x;

        const float* rec = slab + ((size_t)p << 4);
        const float2 ga = *(const float2*)(rec + 2 * bi);    // channels 2bi, 2bi+1
        const float2 gb = *(const float2*)(rec + 2 * bj);    // channels 2bj, 2bj+1

        det.x = x + (w0 * ga.x + w1 * gb.x);
        det.y = y + (w0 * ga.y + w1 * gb.y);
    }

    ((float2*)out)[tid] = det;
}

// ---------------------------------------------------------------------------
// Fallback (original plane-layout kernel) if ws is too small.
// ---------------------------------------------------------------------------
__global__ __launch_bounds__(256) void CPN_fallback_kernel(
    const float* __restrict__ det_in,
    const float* __restrict__ refinement,
    const float* __restrict__ sampling,
    const int*   __restrict__ bsel,
    float*       __restrict__ out)
{
    const int tid = blockIdx.x * blockDim.x + threadIdx.x;
    const int s = tid & (NSAMP - 1);
    const int d = tid >> 7;

    float2 det = ((const float2*)det_in)[tid];
    const int bb = bsel[d];

    const float base = sampling[s] * (float)NBUCK;
    const float bf   = floorf(base);
    const float frac = base - bf;
    const float w0   = 1.0f - frac;
    const float w1   = frac;
    int bi = (int)bf;
    if (bi >= NBUCK) bi -= NBUCK;
    if (bi < 0)      bi  = 0;
    int bj = bi + 1; if (bj >= NBUCK) bj -= NBUCK;

    const size_t plane = (size_t)PLANE;
    const float* slab = refinement + (size_t)bb * NCHAN * plane;
    const float* c0 = slab + (size_t)(2 * bi)     * plane;
    const float* c1 = slab + (size_t)(2 * bi + 1) * plane;
    const float* c2 = slab + (size_t)(2 * bj)     * plane;
    const float* c3 = slab + (size_t)(2 * bj + 1) * plane;

    #pragma unroll
    for (int l = 0; l < NLOOP; ++l) {
        float x = rintf(det.x);
        float y = rintf(det.y);
        x = fminf(fmaxf(x, 0.0f), (float)(WREF - 1));
        y = fminf(fmaxf(y, 0.0f), (float)(HREF - 1));
        const int p = (int)y * WREF + (int)x;
        det.x = x + (w0 * c0[p] + w1 * c2[p]);
        det.y = y + (w0 * c1[p] + w1 * c3[p]);
    }

    ((float2*)out)[tid] = det;
}

extern "C" void kernel_launch(void* const* d_in, const int* in_sizes, int n_in,
                              void* d_out, int out_size, void* d_ws, size_t ws_size,
                              hipStream_t stream) {
    const float* det_indices = (const float*)d_in[0];
    const float* refinement  = (const float*)d_in[1];
    const float* sampling    = (const float*)d_in[2];
    const int*   b           = (const int*)  d_in[3];
    float* out = (float*)d_out;

    const size_t need = (size_t)BATCH * PLANE * RECSZ * sizeof(float);  // 64 MB

    const int total = NDET * NSAMP;          // 524288 threads
    const int block = 256;
    const int grid  = total / block;         // 2048 blocks

    if (ws_size >= need) {
        float* ws = (float*)d_ws;
        const int tp_total = BATCH * PLANE;  // 1048576
        CPN_transpose_kernel<<<tp_total / block, block, 0, stream>>>(refinement, ws);
        CPN_4492535791617_kernel<<<grid, block, 0, stream>>>(
            det_indices, ws, sampling, b, out);
    } else {
        CPN_fallback_kernel<<<grid, block, 0, stream>>>(
            det_indices, refinement, sampling, b, out);
    }
}